// Round 2
// baseline (1466.891 us; speedup 1.0000x reference)
//
#include <hip/hip_runtime.h>
#include <hip/hip_bf16.h>

using bf16 = __hip_bfloat16;
typedef unsigned short ushort_t;
typedef unsigned int uint_t;

constexpr int B = 2, T = 200;
constexpr int N0 = 2048, N1 = 512, N2 = 128, N3 = 64;
constexpr int E0 = 16384, E1 = 8192, E2 = 2048;

// runtime-dtype load: bf=1 -> bf16, bf=0 -> fp32
__device__ __forceinline__ float ldx(const void* p, long i, int bf) {
  if (bf) {
    uint_t v = (uint_t)(((const ushort_t*)p)[i]) << 16;
    float f; __builtin_memcpy(&f, &v, 4); return f;
  }
  return ((const float*)p)[i];
}
__device__ __forceinline__ float rdf(const float* p) { return *p; }
__device__ __forceinline__ float rdf(const bf16* p) { return __bfloat162float(*p); }
__device__ __forceinline__ void stf(float* p, float v) { *p = v; }
__device__ __forceinline__ void stf(bf16* p, float v) { *p = __float2bfloat16(v); }

// ---------- setup kernels ----------
__global__ void k_zero_ints(int* p, int n) {
  int i = blockIdx.x * 256 + threadIdx.x;
  if (i < n) p[i] = 0;
}

// dtype probe: ea0 is uniform[0,1]. As true bf16 all 128 halves decode in [0,1];
// as fp32-misread only ~80/128 do.
__global__ void k_probe(const ushort_t* ea, int* flag) {
  if (threadIdx.x == 0 && blockIdx.x == 0) {
    int c = 0;
    for (int i = 0; i < 128; ++i) {
      uint_t v = (uint_t)ea[i] << 16;
      float f; __builtin_memcpy(&f, &v, 4);
      if (f >= 0.f && f <= 1.0f) c++;
    }
    *flag = (c >= 120) ? 1 : 0;
  }
}

// normalize all float-dtype params to fp32 in ws
__global__ void k_cvtall(const void* x, const void* Wk1, const void* Wr1,
                         const void* Wk2, const void* Wr2,
                         const void* Wk3, const void* Wr3,
                         const void* W1h, const void* W2h,
                         const void* b1, const void* b2, const void* b3,
                         const void* b1h, const void* b2h,
                         const void* A1, const void* A2, const void* A3,
                         float* dst, const int* flagp) {
  int i = blockIdx.x * 256 + threadIdx.x;
  int bf = *flagp;
  if (i < 819200)       dst[i] = ldx(x,   i, bf);
  else if (i < 819248)  dst[i] = ldx(Wk1, i - 819200, bf);
  else if (i < 819264)  dst[i] = ldx(Wr1, i - 819248, bf);
  else if (i < 820800)  dst[i] = ldx(Wk2, i - 819264, bf);
  else if (i < 821312)  dst[i] = ldx(Wr2, i - 820800, bf);
  else if (i < 827456)  dst[i] = ldx(Wk3, i - 821312, bf);
  else if (i < 829504)  dst[i] = ldx(Wr3, i - 827456, bf);
  else if (i < 837696)  dst[i] = ldx(W1h, i - 829504, bf);
  else if (i < 845888)  dst[i] = ldx(W2h, i - 837696, bf);
  else if (i < 845904)  dst[i] = ldx(b1,  i - 845888, bf);
  else if (i < 845936)  dst[i] = ldx(b2,  i - 845904, bf);
  else if (i < 846000)  dst[i] = ldx(b3,  i - 845936, bf);
  else if (i < 846128)  dst[i] = ldx(b1h, i - 846000, bf);
  else if (i < 846192)  dst[i] = ldx(b2h, i - 846128, bf);
  else if (i < 846201)  dst[i] = ldx(A1,  i - 846192, bf);
  else if (i < 846210)  dst[i] = ldx(A2,  i - 846201, bf);
  else if (i < 846219)  dst[i] = ldx(A3,  i - 846210, bf);
}

__global__ void k_hist3(const int* d0, const int* d1, const int* d2,
                        int* c0, int* c1, int* c2) {
  int i = blockIdx.x * 256 + threadIdx.x;
  if (i < E0) atomicAdd(&c0[d0[i]], 1);
  if (i < E1) atomicAdd(&c1[d1[i]], 1);
  if (i < E2) atomicAdd(&c2[d2[i]], 1);
}

__global__ void k_scan3(const int* c0, int* o0, int* u0,
                        const int* c1, int* o1, int* u1,
                        const int* c2, int* o2, int* u2) {
  const int* cnt; int* off; int* cur; int N;
  if (blockIdx.x == 0)      { cnt = c0; off = o0; cur = u0; N = N0; }
  else if (blockIdx.x == 1) { cnt = c1; off = o1; cur = u1; N = N1; }
  else                      { cnt = c2; off = o2; cur = u2; N = N2; }
  int tid = threadIdx.x;
  int chunk = (N + 63) >> 6;
  int base = tid * chunk;
  int s = 0;
  for (int j = 0; j < chunk; ++j) { int idx = base + j; if (idx < N) s += cnt[idx]; }
  int pre = s;
  for (int d = 1; d < 64; d <<= 1) {
    int v = __shfl_up(pre, d, 64);
    if (tid >= d) pre += v;
  }
  int run = pre - s;
  for (int j = 0; j < chunk; ++j) {
    int idx = base + j;
    if (idx < N) { off[idx] = run; cur[idx] = run; run += cnt[idx]; }
  }
  if (tid == 63) off[N] = run;
}

__global__ void k_fill3(const int* d0, int* u0, int* e0l,
                        const int* d1, int* u1, int* e1l,
                        const int* d2, int* u2, int* e2l) {
  int i = blockIdx.x * 256 + threadIdx.x;
  if (i < E0) { int p = atomicAdd(&u0[d0[i]], 1); e0l[p] = i; }
  if (i < E1) { int p = atomicAdd(&u1[d1[i]], 1); e1l[p] = i; }
  if (i < E2) { int p = atomicAdd(&u2[d2[i]], 1); e2l[p] = i; }
}

__device__ __forceinline__ void bw_one(const void* ea, int bf, const float* A,
                                       float* bw, int e) {
  float a0 = ldx(ea, e*3+0, bf), a1 = ldx(ea, e*3+1, bf), a2 = ldx(ea, e*3+2, bf);
  float l0 = a0*A[0] + a1*A[3] + a2*A[6];
  float l1 = a0*A[1] + a1*A[4] + a2*A[7];
  float l2 = a0*A[2] + a1*A[5] + a2*A[8];
  float m = fmaxf(l0, fmaxf(l1, l2));
  float x0 = expf(l0 - m), x1 = expf(l1 - m), x2 = expf(l2 - m);
  float inv = 1.0f / (x0 + x1 + x2);
  bw[e*3+0] = x0*inv; bw[e*3+1] = x1*inv; bw[e*3+2] = x2*inv;
}

__global__ void k_bw3(const void* ea0, const void* ea1, const void* ea2,
                      const float* Am, float* bw0, float* bw1, float* bw2,
                      const int* flagp) {
  int bf = *flagp;
  int i = blockIdx.x * 256 + threadIdx.x;
  if (i < E0) bw_one(ea0, bf, Am + 0,  bw0, i);
  if (i < E1) bw_one(ea1, bf, Am + 9,  bw1, i);
  if (i < E2) bw_one(ea2, bf, Am + 18, bw2, i);
}

// transpose pool matrices to [N][M] fp32
__global__ void k_ptrans(const void* P01, const void* P12, const void* P23,
                         float* t1, float* t2, float* t3, const int* flagp) {
  int bf = *flagp;
  int i = blockIdx.x * 256 + threadIdx.x;
  if (i < 512 * 2048) { int m = i >> 11, n = i & 2047; t1[n * 512 + m] = ldx(P01, i, bf); }
  if (i < 128 * 512)  { int m = i >> 9,  n = i & 511;  t2[n * 128 + m] = ldx(P12, i, bf); }
  if (i < 64 * 128)   { int m = i >> 7,  n = i & 127;  t3[n * 64 + m]  = ldx(P23, i, bf); }
}

// ---------- level-1 gather (Cin=1, fp32 in/out) ----------
__global__ __launch_bounds__(256) void k_gather1(const float* x, const int* src,
    const int* off, const int* elist, const int* cnt, const float* bw, float* zx) {
  int n = blockIdx.y, b = blockIdx.z;
  int t = threadIdx.x;
  if (t >= T) return;
  int beg = off[n], end = off[n + 1];
  float a0 = 0.f, a1 = 0.f, a2 = 0.f;
  for (int q = beg; q < end; ++q) {
    int e = elist[q];
    int s = src[e];
    float xv = x[(b * N0 + s) * T + t];
    a0 += bw[e*3+0] * xv; a1 += bw[e*3+1] * xv; a2 += bw[e*3+2] * xv;
  }
  int c = cnt[n];
  float inv = 1.f / (float)(c > 0 ? c : 1);
  float* zp = zx + ((long)(b * N0 + n)) * 4 * T + t;
  zp[0 * T] = a0 * inv;
  zp[1 * T] = a1 * inv;
  zp[2 * T] = a2 * inv;
  zp[3 * T] = x[(b * N0 + n) * T + t];
}

// ---------- generic gather (fp32 in, TOut out) ----------
template<int CIN, int CPI, typename TOut>
__global__ __launch_bounds__(256) void k_gather(const float* x, const int* src,
    const int* off, const int* elist, const int* cnt, const float* bw,
    TOut* zx, int N) {
  int tx = threadIdx.x & 63, iy = threadIdx.x >> 6;
  int t = blockIdx.x * 64 + tx;
  int n = blockIdx.y, b = blockIdx.z;
  if (t >= T) return;
  int beg = off[n], end = off[n + 1];
  float acc[3][CPI];
#pragma unroll
  for (int k = 0; k < 3; ++k)
#pragma unroll
    for (int j = 0; j < CPI; ++j) acc[k][j] = 0.f;
  for (int q = beg; q < end; ++q) {
    int e = elist[q];
    int s = src[e];
    float w0 = bw[e*3+0], w1 = bw[e*3+1], w2 = bw[e*3+2];
    const float* xp = x + ((long)(b * N + s) * CIN) * T + t;
#pragma unroll
    for (int j = 0; j < CPI; ++j) {
      int i = iy * CPI + j;
      float xv = xp[i * T];
      acc[0][j] += w0 * xv; acc[1][j] += w1 * xv; acc[2][j] += w2 * xv;
    }
  }
  int c = cnt[n];
  float inv = 1.f / (float)(c > 0 ? c : 1);
  TOut* zp = zx + ((long)(b * N + n) * 4 * CIN) * T + t;
  const float* xs = x + ((long)(b * N + n) * CIN) * T + t;
#pragma unroll
  for (int j = 0; j < CPI; ++j) {
    int i = iy * CPI + j;
    stf(zp + (0 * CIN + i) * T, acc[0][j] * inv);
    stf(zp + (1 * CIN + i) * T, acc[1][j] * inv);
    stf(zp + (2 * CIN + i) * T, acc[2][j] * inv);
    stf(zp + (3 * CIN + i) * T, xs[i * T]);
  }
}

// ---------- channel mix ----------
template<int C, int O, int ACT, typename TIn, typename TOut>
__global__ __launch_bounds__(256) void k_cmix(const TIn* in, const float* W,
                                              const float* bias, TOut* out, int N) {
  constexpr int OP = O / 4;
  __shared__ float in_l[C * 64];
  __shared__ float w_l[C * O];
  int tid = threadIdx.x;
  int tx = tid & 63, ty = tid >> 6;
  int t0 = blockIdx.x * 64;
  int n = blockIdx.y, b = blockIdx.z;
  for (int i = tid; i < C * O; i += 256) w_l[i] = W[i];
  const TIn* ip = in + ((long)(b * N + n) * C) * T;
  for (int i = tid; i < C * 64; i += 256) {
    int c = i >> 6, tt = i & 63;
    in_l[i] = (t0 + tt < T) ? rdf(ip + c * T + t0 + tt) : 0.f;
  }
  __syncthreads();
  int o0 = ty * OP;
  float acc[OP];
#pragma unroll
  for (int oo = 0; oo < OP; ++oo) acc[oo] = 0.f;
  for (int c = 0; c < C; ++c) {
    float xv = in_l[c * 64 + tx];
    const float* wrow = &w_l[c * O + o0];
#pragma unroll
    for (int oo = 0; oo < OP; ++oo) acc[oo] += xv * wrow[oo];
  }
  int t = t0 + tx;
  if (t < T) {
    TOut* op = out + ((long)(b * N + n) * O) * T + t;
#pragma unroll
    for (int oo = 0; oo < OP; ++oo) {
      int o = o0 + oo;
      float v = acc[oo] + bias[o];
      if (ACT == 0) v = v > 0.f ? v : (expf(v) - 1.f);
      else          v = tanhf(v);
      stf(op + o * T, v);
    }
  }
}

// ---------- pool GEMM: out[b,m,f] = sum_n Pt[n,m] * h[b,n,f] ----------
template<int FB, int FW, typename TIn>
__global__ __launch_bounds__(256) void k_pool(const TIn* h, const float* Pt,
                                              float* out, int M, int Nn, int F) {
  __shared__ __align__(16) float pA[16 * 64];
  __shared__ __align__(16) float pB[16 * FB];
  int tid = threadIdx.x;
  int f0 = blockIdx.x * FB;
  int m0 = blockIdx.y * 64;
  int b = blockIdx.z;
  int r = tid >> 5;
  int cx = tid & 31;
  float acc[8][FW];
#pragma unroll
  for (int mi = 0; mi < 8; ++mi)
#pragma unroll
    for (int fi = 0; fi < FW; ++fi) acc[mi][fi] = 0.f;

  for (int k0 = 0; k0 < Nn; k0 += 16) {
    for (int i = tid; i < 16 * 64; i += 256) {
      int k = i >> 6, m = i & 63;
      pA[i] = Pt[(long)(k0 + k) * M + m0 + m];
    }
    for (int i = tid; i < 16 * FB; i += 256) {
      int k = i / FB, f = i % FB;
      int fg = f0 + f;
      pB[i] = (fg < F) ? rdf(&h[((long)(b * Nn + k0 + k)) * F + fg]) : 0.f;
    }
    __syncthreads();
#pragma unroll
    for (int k = 0; k < 16; ++k) {
      const float4* ap = (const float4*)&pA[k * 64 + r * 8];
      float4 a0 = ap[0], a1 = ap[1];
      float av[8] = {a0.x, a0.y, a0.z, a0.w, a1.x, a1.y, a1.z, a1.w};
      float bv[FW];
#pragma unroll
      for (int fi = 0; fi < FW; ++fi) bv[fi] = pB[k * FB + cx + 32 * fi];
#pragma unroll
      for (int mi = 0; mi < 8; ++mi)
#pragma unroll
        for (int fi = 0; fi < FW; ++fi) acc[mi][fi] += av[mi] * bv[fi];
    }
    __syncthreads();
  }
#pragma unroll
  for (int mi = 0; mi < 8; ++mi) {
    int m = m0 + r * 8 + mi;
    float* op = out + ((long)(b * M + m)) * F;
#pragma unroll
    for (int fi = 0; fi < FW; ++fi) {
      int f = f0 + cx + 32 * fi;
      if (f < F) op[f] = acc[mi][fi];
    }
  }
}

// final store: dtype per flag
__global__ void k_store(const float* mu, void* out, int n, const int* flagp) {
  int i = blockIdx.x * 256 + threadIdx.x;
  if (i >= n) return;
  if (*flagp) ((bf16*)out)[i] = __float2bfloat16(mu[i]);
  else        ((float*)out)[i] = mu[i];
}

extern "C" void kernel_launch(void* const* d_in, const int* in_sizes, int n_in,
                              void* d_out, int out_size, void* d_ws, size_t ws_size,
                              hipStream_t stream) {
  const int* ei0 = (const int*)d_in[1];
  const int* ei1 = (const int*)d_in[3];
  const int* ei2 = (const int*)d_in[5];

  char* base = (char*)d_ws;
  int* I = (int*)base;
  int* cnt0 = I;         int* off0 = I + 2048;  int* cur0 = I + 4112;  int* el0 = I + 6160;
  int* cnt1 = I + 22544; int* off1 = I + 23056; int* cur1 = I + 23584; int* el1 = I + 24096;
  int* cnt2 = I + 32288; int* off2 = I + 32416; int* cur2 = I + 32560; int* el2 = I + 32688;
  int* flagp = I + 40448;
  float* Fb = (float*)(base + 163840);
  // conversion region offsets (floats)
  float* xc  = Fb + 0;
  float* wc1 = Fb + 819200;
  float* wc2 = Fb + 819264;
  float* wc3 = Fb + 821312;
  float* w1h = Fb + 829504;
  float* w2h = Fb + 837696;
  float* bias= Fb + 845888;   // b1@0 b2@16 b3@48 b1h@112 b2h@240
  float* Am  = Fb + 846192;   // A1@0 A2@9 A3@18
  float* bw0 = Fb + 846220;
  float* bw1 = Fb + 895372;
  float* bw2 = Fb + 919948;
  float* pt1 = Fb + 926092;
  float* pt2 = Fb + 1974668;
  float* pt3 = Fb + 2040204;
  char* Aa = base + 8357888;    // arena A: 13,107,200 B
  char* Bb = base + 21465088;   // arena B: 26,214,400 B  (ws total ~45.5 MiB)

  // setup
  k_zero_ints<<<160, 256, 0, stream>>>(I, 40960);
  k_probe<<<1, 64, 0, stream>>>((const ushort_t*)d_in[2], flagp);
  k_cvtall<<<3306, 256, 0, stream>>>(d_in[0], d_in[8], d_in[9], d_in[12], d_in[13],
                                     d_in[16], d_in[17], d_in[22], d_in[24],
                                     d_in[10], d_in[14], d_in[18], d_in[23], d_in[25],
                                     d_in[7], d_in[11], d_in[15], Fb, flagp);
  k_hist3<<<64, 256, 0, stream>>>(ei0 + E0, ei1 + E1, ei2 + E2, cnt0, cnt1, cnt2);
  k_scan3<<<3, 64, 0, stream>>>(cnt0, off0, cur0, cnt1, off1, cur1, cnt2, off2, cur2);
  k_fill3<<<64, 256, 0, stream>>>(ei0 + E0, cur0, el0, ei1 + E1, cur1, el1, ei2 + E2, cur2, el2);
  k_bw3<<<64, 256, 0, stream>>>(d_in[2], d_in[4], d_in[6], Am, bw0, bw1, bw2, flagp);
  k_ptrans<<<4096, 256, 0, stream>>>(d_in[19], d_in[20], d_in[21], pt1, pt2, pt3, flagp);

  // level 0 -> 1   (zx1:A fp32, h1:B bf16, hp1:A fp32)
  k_gather1<<<dim3(1, N0, B), 256, 0, stream>>>(xc, ei0, off0, el0, cnt0, bw0, (float*)Aa);
  k_cmix<4, 16, 0, float, bf16><<<dim3(4, N0, B), 256, 0, stream>>>((const float*)Aa, wc1, bias + 0, (bf16*)Bb, N0);
  k_pool<256, 8, bf16><<<dim3(13, 8, B), 256, 0, stream>>>((const bf16*)Bb, pt1, (float*)Aa, 512, 2048, 3200);
  // level 1 -> 2   (zx2:B bf16, h2:A bf16, hp2:B fp32)
  k_gather<16, 4, bf16><<<dim3(4, N1, B), 256, 0, stream>>>((const float*)Aa, ei1, off1, el1, cnt1, bw1, (bf16*)Bb, N1);
  k_cmix<64, 32, 0, bf16, bf16><<<dim3(4, N1, B), 256, 0, stream>>>((const bf16*)Bb, wc2, bias + 16, (bf16*)Aa, N1);
  k_pool<128, 4, bf16><<<dim3(50, 2, B), 256, 0, stream>>>((const bf16*)Aa, pt2, (float*)Bb, 128, 512, 6400);
  // level 2 -> 3   (zx3:A bf16, h3:B fp32, hp3:A fp32)
  k_gather<32, 8, bf16><<<dim3(4, N2, B), 256, 0, stream>>>((const float*)Bb, ei2, off2, el2, cnt2, bw2, (bf16*)Aa, N2);
  k_cmix<128, 64, 0, bf16, float><<<dim3(4, N2, B), 256, 0, stream>>>((const bf16*)Aa, wc3, bias + 48, (float*)Bb, N2);
  k_pool<128, 4, float><<<dim3(100, 1, B), 256, 0, stream>>>((const float*)Bb, pt3, (float*)Aa, 64, 128, 12800);
  // head  (g:B fp32, mu:A fp32)
  k_cmix<64, 128, 0, float, float><<<dim3(4, N3, B), 256, 0, stream>>>((const float*)Aa, w1h, bias + 112, (float*)Bb, N3);
  k_cmix<128, 64, 1, float, float><<<dim3(4, N3, B), 256, 0, stream>>>((const float*)Bb, w2h, bias + 240, (float*)Aa, N3);
  k_store<<<6400, 256, 0, stream>>>((const float*)Aa, d_out, 1638400, flagp);
}

// Round 3
// 430.664 us; speedup vs baseline: 3.4061x; 3.4061x over previous
//
#include <hip/hip_runtime.h>
#include <hip/hip_bf16.h>

using bf16 = __hip_bfloat16;
typedef unsigned short ushort_t;
typedef unsigned int uint_t;

constexpr int B = 2, T = 200;
constexpr int N0 = 2048, N1 = 512, N2 = 128, N3 = 64;
constexpr int E0 = 16384, E1 = 8192, E2 = 2048;

typedef __attribute__((ext_vector_type(8))) short bf16x8;
typedef __attribute__((ext_vector_type(4))) float f32x4;

// runtime-dtype load: bf=1 -> bf16, bf=0 -> fp32
__device__ __forceinline__ float ldx(const void* p, long i, int bf) {
  if (bf) {
    uint_t v = (uint_t)(((const ushort_t*)p)[i]) << 16;
    float f; __builtin_memcpy(&f, &v, 4); return f;
  }
  return ((const float*)p)[i];
}
__device__ __forceinline__ float rdf(const float* p) { return *p; }
__device__ __forceinline__ float rdf(const bf16* p) { return __bfloat162float(*p); }
__device__ __forceinline__ void stf(float* p, float v) { *p = v; }
__device__ __forceinline__ void stf(bf16* p, float v) { *p = __float2bfloat16(v); }
__device__ __forceinline__ ushort_t f2bfu(float v) {
  bf16 h = __float2bfloat16(v); ushort_t u; __builtin_memcpy(&u, &h, 2); return u;
}

// ---------- setup kernels ----------
__global__ void k_zero_ints(int* p, int n) {
  int i = blockIdx.x * 256 + threadIdx.x;
  if (i < n) p[i] = 0;
}

// dtype probe: ea0 is uniform[0,1]. As true bf16 all 128 halves decode in [0,1].
__global__ void k_probe(const ushort_t* ea, int* flag) {
  if (threadIdx.x == 0 && blockIdx.x == 0) {
    int c = 0;
    for (int i = 0; i < 128; ++i) {
      uint_t v = (uint_t)ea[i] << 16;
      float f; __builtin_memcpy(&f, &v, 4);
      if (f >= 0.f && f <= 1.0f) c++;
    }
    *flag = (c >= 120) ? 1 : 0;
  }
}

// normalize all float-dtype params to fp32 in ws
__global__ void k_cvtall(const void* x, const void* Wk1, const void* Wr1,
                         const void* Wk2, const void* Wr2,
                         const void* Wk3, const void* Wr3,
                         const void* W1h, const void* W2h,
                         const void* b1, const void* b2, const void* b3,
                         const void* b1h, const void* b2h,
                         const void* A1, const void* A2, const void* A3,
                         float* dst, const int* flagp) {
  int i = blockIdx.x * 256 + threadIdx.x;
  int bf = *flagp;
  if (i < 819200)       dst[i] = ldx(x,   i, bf);
  else if (i < 819248)  dst[i] = ldx(Wk1, i - 819200, bf);
  else if (i < 819264)  dst[i] = ldx(Wr1, i - 819248, bf);
  else if (i < 820800)  dst[i] = ldx(Wk2, i - 819264, bf);
  else if (i < 821312)  dst[i] = ldx(Wr2, i - 820800, bf);
  else if (i < 827456)  dst[i] = ldx(Wk3, i - 821312, bf);
  else if (i < 829504)  dst[i] = ldx(Wr3, i - 827456, bf);
  else if (i < 837696)  dst[i] = ldx(W1h, i - 829504, bf);
  else if (i < 845888)  dst[i] = ldx(W2h, i - 837696, bf);
  else if (i < 845904)  dst[i] = ldx(b1,  i - 845888, bf);
  else if (i < 845936)  dst[i] = ldx(b2,  i - 845904, bf);
  else if (i < 846000)  dst[i] = ldx(b3,  i - 845936, bf);
  else if (i < 846128)  dst[i] = ldx(b1h, i - 846000, bf);
  else if (i < 846192)  dst[i] = ldx(b2h, i - 846128, bf);
  else if (i < 846201)  dst[i] = ldx(A1,  i - 846192, bf);
  else if (i < 846210)  dst[i] = ldx(A2,  i - 846201, bf);
  else if (i < 846219)  dst[i] = ldx(A3,  i - 846210, bf);
}

__global__ void k_hist3(const int* d0, const int* d1, const int* d2,
                        int* c0, int* c1, int* c2) {
  int i = blockIdx.x * 256 + threadIdx.x;
  if (i < E0) atomicAdd(&c0[d0[i]], 1);
  if (i < E1) atomicAdd(&c1[d1[i]], 1);
  if (i < E2) atomicAdd(&c2[d2[i]], 1);
}

__global__ void k_scan3(const int* c0, int* o0, int* u0,
                        const int* c1, int* o1, int* u1,
                        const int* c2, int* o2, int* u2) {
  const int* cnt; int* off; int* cur; int N;
  if (blockIdx.x == 0)      { cnt = c0; off = o0; cur = u0; N = N0; }
  else if (blockIdx.x == 1) { cnt = c1; off = o1; cur = u1; N = N1; }
  else                      { cnt = c2; off = o2; cur = u2; N = N2; }
  int tid = threadIdx.x;
  int chunk = (N + 63) >> 6;
  int base = tid * chunk;
  int s = 0;
  for (int j = 0; j < chunk; ++j) { int idx = base + j; if (idx < N) s += cnt[idx]; }
  int pre = s;
  for (int d = 1; d < 64; d <<= 1) {
    int v = __shfl_up(pre, d, 64);
    if (tid >= d) pre += v;
  }
  int run = pre - s;
  for (int j = 0; j < chunk; ++j) {
    int idx = base + j;
    if (idx < N) { off[idx] = run; cur[idx] = run; run += cnt[idx]; }
  }
  if (tid == 63) off[N] = run;
}

__global__ void k_fill3(const int* d0, int* u0, int* e0l,
                        const int* d1, int* u1, int* e1l,
                        const int* d2, int* u2, int* e2l) {
  int i = blockIdx.x * 256 + threadIdx.x;
  if (i < E0) { int p = atomicAdd(&u0[d0[i]], 1); e0l[p] = i; }
  if (i < E1) { int p = atomicAdd(&u1[d1[i]], 1); e1l[p] = i; }
  if (i < E2) { int p = atomicAdd(&u2[d2[i]], 1); e2l[p] = i; }
}

__device__ __forceinline__ void bw_one(const void* ea, int bf, const float* A,
                                       float* bw, int e) {
  float a0 = ldx(ea, e*3+0, bf), a1 = ldx(ea, e*3+1, bf), a2 = ldx(ea, e*3+2, bf);
  float l0 = a0*A[0] + a1*A[3] + a2*A[6];
  float l1 = a0*A[1] + a1*A[4] + a2*A[7];
  float l2 = a0*A[2] + a1*A[5] + a2*A[8];
  float m = fmaxf(l0, fmaxf(l1, l2));
  float x0 = expf(l0 - m), x1 = expf(l1 - m), x2 = expf(l2 - m);
  float inv = 1.0f / (x0 + x1 + x2);
  bw[e*3+0] = x0*inv; bw[e*3+1] = x1*inv; bw[e*3+2] = x2*inv;
}

__global__ void k_bw3(const void* ea0, const void* ea1, const void* ea2,
                      const float* Am, float* bw0, float* bw1, float* bw2,
                      const int* flagp) {
  int bf = *flagp;
  int i = blockIdx.x * 256 + threadIdx.x;
  if (i < E0) bw_one(ea0, bf, Am + 0,  bw0, i);
  if (i < E1) bw_one(ea1, bf, Am + 9,  bw1, i);
  if (i < E2) bw_one(ea2, bf, Am + 18, bw2, i);
}

// P matrices -> bf16 [M][K] (original layout; no transpose needed for MFMA A-operand)
__global__ void k_pcvt(const void* P01, const void* P12, const void* P23,
                       ushort_t* p1, ushort_t* p2, ushort_t* p3, const int* flagp) {
  int bf = *flagp;
  int i = blockIdx.x * 256 + threadIdx.x;
  if (i < 512 * 2048) p1[i] = f2bfu(ldx(P01, i, bf));
  if (i < 128 * 512)  p2[i] = f2bfu(ldx(P12, i, bf));
  if (i < 64 * 128)   p3[i] = f2bfu(ldx(P23, i, bf));
}

// ---------- level-1 gather (Cin=1, fp32 in/out) ----------
__global__ __launch_bounds__(256) void k_gather1(const float* x, const int* src,
    const int* off, const int* elist, const int* cnt, const float* bw, float* zx) {
  int n = blockIdx.y, b = blockIdx.z;
  int t = threadIdx.x;
  if (t >= T) return;
  int beg = off[n], end = off[n + 1];
  float a0 = 0.f, a1 = 0.f, a2 = 0.f;
  for (int q = beg; q < end; ++q) {
    int e = elist[q];
    int s = src[e];
    float xv = x[(b * N0 + s) * T + t];
    a0 += bw[e*3+0] * xv; a1 += bw[e*3+1] * xv; a2 += bw[e*3+2] * xv;
  }
  int c = cnt[n];
  float inv = 1.f / (float)(c > 0 ? c : 1);
  float* zp = zx + ((long)(b * N0 + n)) * 4 * T + t;
  zp[0 * T] = a0 * inv;
  zp[1 * T] = a1 * inv;
  zp[2 * T] = a2 * inv;
  zp[3 * T] = x[(b * N0 + n) * T + t];
}

// ---------- generic gather (fp32 in, TOut out) ----------
template<int CIN, int CPI, typename TOut>
__global__ __launch_bounds__(256) void k_gather(const float* x, const int* src,
    const int* off, const int* elist, const int* cnt, const float* bw,
    TOut* zx, int N) {
  int tx = threadIdx.x & 63, iy = threadIdx.x >> 6;
  int t = blockIdx.x * 64 + tx;
  int n = blockIdx.y, b = blockIdx.z;
  if (t >= T) return;
  int beg = off[n], end = off[n + 1];
  float acc[3][CPI];
#pragma unroll
  for (int k = 0; k < 3; ++k)
#pragma unroll
    for (int j = 0; j < CPI; ++j) acc[k][j] = 0.f;
  for (int q = beg; q < end; ++q) {
    int e = elist[q];
    int s = src[e];
    float w0 = bw[e*3+0], w1 = bw[e*3+1], w2 = bw[e*3+2];
    const float* xp = x + ((long)(b * N + s) * CIN) * T + t;
#pragma unroll
    for (int j = 0; j < CPI; ++j) {
      int i = iy * CPI + j;
      float xv = xp[i * T];
      acc[0][j] += w0 * xv; acc[1][j] += w1 * xv; acc[2][j] += w2 * xv;
    }
  }
  int c = cnt[n];
  float inv = 1.f / (float)(c > 0 ? c : 1);
  TOut* zp = zx + ((long)(b * N + n) * 4 * CIN) * T + t;
  const float* xs = x + ((long)(b * N + n) * CIN) * T + t;
#pragma unroll
  for (int j = 0; j < CPI; ++j) {
    int i = iy * CPI + j;
    stf(zp + (0 * CIN + i) * T, acc[0][j] * inv);
    stf(zp + (1 * CIN + i) * T, acc[1][j] * inv);
    stf(zp + (2 * CIN + i) * T, acc[2][j] * inv);
    stf(zp + (3 * CIN + i) * T, xs[i * T]);
  }
}

// ---------- channel mix ----------
template<int C, int O, int ACT, typename TIn, typename TOut>
__global__ __launch_bounds__(256) void k_cmix(const TIn* in, const float* W,
                                              const float* bias, TOut* out, int N) {
  constexpr int OP = O / 4;
  __shared__ float in_l[C * 64];
  __shared__ float w_l[C * O];
  int tid = threadIdx.x;
  int tx = tid & 63, ty = tid >> 6;
  int t0 = blockIdx.x * 64;
  int n = blockIdx.y, b = blockIdx.z;
  for (int i = tid; i < C * O; i += 256) w_l[i] = W[i];
  const TIn* ip = in + ((long)(b * N + n) * C) * T;
  for (int i = tid; i < C * 64; i += 256) {
    int c = i >> 6, tt = i & 63;
    in_l[i] = (t0 + tt < T) ? rdf(ip + c * T + t0 + tt) : 0.f;
  }
  __syncthreads();
  int o0 = ty * OP;
  float acc[OP];
#pragma unroll
  for (int oo = 0; oo < OP; ++oo) acc[oo] = 0.f;
  for (int c = 0; c < C; ++c) {
    float xv = in_l[c * 64 + tx];
    const float* wrow = &w_l[c * O + o0];
#pragma unroll
    for (int oo = 0; oo < OP; ++oo) acc[oo] += xv * wrow[oo];
  }
  int t = t0 + tx;
  if (t < T) {
    TOut* op = out + ((long)(b * N + n) * O) * T + t;
#pragma unroll
    for (int oo = 0; oo < OP; ++oo) {
      int o = o0 + oo;
      float v = acc[oo] + bias[o];
      if (ACT == 0) v = v > 0.f ? v : (expf(v) - 1.f);
      else          v = tanhf(v);
      stf(op + o * T, v);
    }
  }
}

// ---------- MFMA pool GEMM: out[b,m,f] = sum_k Pb[m,k] * h[b,k,f] ----------
// Pb bf16 [M][K]; h bf16 [B][K][F]; 256 thr = 4 waves.
// Block tile: BM=64*WMT (m), 64 (f), K-chunk 64. Wave: WMT m-tiles x 4 f-tiles.
// LDS tiles stored [outer][k] with k-group XOR swizzle (kc ^= outer&7) so both
// transposed b128 writes and frag b128 reads sit at the LDS data floor.
template<int WMT, typename TOut>
__global__ __launch_bounds__(256) void k_pool_mfma(const ushort_t* Pb, const ushort_t* h,
                                                   TOut* out, int M, int K, int F) {
  constexpr int BM = 64 * WMT;
  __shared__ __align__(16) ushort_t As[BM * 64];
  __shared__ __align__(16) ushort_t Bs[64 * 64];
  int tid = threadIdx.x;
  int w = tid >> 6, l = tid & 63;
  int lf = l & 15, quad = l >> 4;
  int f0 = blockIdx.x * 64;
  int m0 = blockIdx.y * BM;
  int b = blockIdx.z;
  f32x4 acc[WMT][4];
#pragma unroll
  for (int wt = 0; wt < WMT; ++wt)
#pragma unroll
    for (int ft = 0; ft < 4; ++ft) acc[wt][ft] = (f32x4){0.f, 0.f, 0.f, 0.f};

  for (int k0 = 0; k0 < K; k0 += 64) {
    // stage A: coalesced b128 rows -> swizzled LDS
#pragma unroll
    for (int it = 0; it < BM / 32; ++it) {
      int cc = tid + 256 * it;
      int m = cc >> 3, kc = cc & 7;
      uint4 v = *(const uint4*)(Pb + (long)(m0 + m) * K + k0 + kc * 8);
      *(uint4*)(As + m * 64 + ((kc ^ (m & 7)) * 8)) = v;
    }
    // stage B transposed: per-thread fixed f, 16 k's (128B global segments)
    {
      int f = tid & 63, kb = (tid >> 6) * 16;
      const ushort_t* hp = h + ((long)(b * K + k0 + kb)) * F + f0 + f;
      ushort_t r[16];
#pragma unroll
      for (int i = 0; i < 16; ++i) r[i] = hp[(long)i * F];
      int kc0 = kb >> 3;
      *(uint4*)(Bs + f * 64 + ((kc0 ^ (f & 7)) * 8)) = *(uint4*)&r[0];
      *(uint4*)(Bs + f * 64 + (((kc0 + 1) ^ (f & 7)) * 8)) = *(uint4*)&r[8];
    }
    __syncthreads();
#pragma unroll
    for (int ks = 0; ks < 2; ++ks) {
      int kc = ks * 4 + quad;
      bf16x8 bfr[4];
#pragma unroll
      for (int ft = 0; ft < 4; ++ft) {
        int fl = ft * 16 + lf;
        bfr[ft] = *(const bf16x8*)(Bs + fl * 64 + ((kc ^ (fl & 7)) * 8));
      }
#pragma unroll
      for (int wt = 0; wt < WMT; ++wt) {
        int ml = wt * 64 + w * 16 + lf;
        bf16x8 afr = *(const bf16x8*)(As + ml * 64 + ((kc ^ (ml & 7)) * 8));
#pragma unroll
        for (int ft = 0; ft < 4; ++ft)
          acc[wt][ft] = __builtin_amdgcn_mfma_f32_16x16x32_bf16(afr, bfr[ft], acc[wt][ft], 0, 0, 0);
      }
    }
    __syncthreads();
  }
  // epilogue: C/D layout col=lane&15, row=quad*4+reg
#pragma unroll
  for (int wt = 0; wt < WMT; ++wt) {
#pragma unroll
    for (int r = 0; r < 4; ++r) {
      int m = m0 + wt * 64 + w * 16 + quad * 4 + r;
      TOut* op = out + ((long)(b * M + m)) * F + f0 + lf;
#pragma unroll
      for (int ft = 0; ft < 4; ++ft)
        stf(op + ft * 16, acc[wt][ft][r]);
    }
  }
}

// final store: dtype per flag
__global__ void k_store(const float* mu, void* out, int n, const int* flagp) {
  int i = blockIdx.x * 256 + threadIdx.x;
  if (i >= n) return;
  if (*flagp) ((bf16*)out)[i] = __float2bfloat16(mu[i]);
  else        ((float*)out)[i] = mu[i];
}

extern "C" void kernel_launch(void* const* d_in, const int* in_sizes, int n_in,
                              void* d_out, int out_size, void* d_ws, size_t ws_size,
                              hipStream_t stream) {
  const int* ei0 = (const int*)d_in[1];
  const int* ei1 = (const int*)d_in[3];
  const int* ei2 = (const int*)d_in[5];

  char* base = (char*)d_ws;
  int* I = (int*)base;
  int* cnt0 = I;         int* off0 = I + 2048;  int* cur0 = I + 4112;  int* el0 = I + 6160;
  int* cnt1 = I + 22544; int* off1 = I + 23056; int* cur1 = I + 23584; int* el1 = I + 24096;
  int* cnt2 = I + 32288; int* off2 = I + 32416; int* cur2 = I + 32560; int* el2 = I + 32688;
  int* flagp = I + 40448;
  float* Fb = (float*)(base + 163840);
  float* xc  = Fb + 0;
  float* wc1 = Fb + 819200;
  float* wc2 = Fb + 819264;
  float* wc3 = Fb + 821312;
  float* w1h = Fb + 829504;
  float* w2h = Fb + 837696;
  float* bias= Fb + 845888;   // b1@0 b2@16 b3@48 b1h@112 b2h@240
  float* Am  = Fb + 846192;   // A1@0 A2@9 A3@18
  float* bw0 = Fb + 846220;
  float* bw1 = Fb + 895372;
  float* bw2 = Fb + 919948;
  ushort_t* Pb1 = (ushort_t*)(Fb + 926092);    // 1048576 ushorts
  ushort_t* Pb2 = (ushort_t*)(Fb + 1974668);   // 65536 ushorts
  ushort_t* Pb3 = (ushort_t*)(Fb + 2040204);   // 8192 ushorts
  char* Aa = base + 8357888;    // arena A: 13,107,200 B
  char* Bb = base + 21465088;   // arena B: 26,214,400 B

  // setup
  k_zero_ints<<<160, 256, 0, stream>>>(I, 40960);
  k_probe<<<1, 64, 0, stream>>>((const ushort_t*)d_in[2], flagp);
  k_cvtall<<<3306, 256, 0, stream>>>(d_in[0], d_in[8], d_in[9], d_in[12], d_in[13],
                                     d_in[16], d_in[17], d_in[22], d_in[24],
                                     d_in[10], d_in[14], d_in[18], d_in[23], d_in[25],
                                     d_in[7], d_in[11], d_in[15], Fb, flagp);
  k_hist3<<<64, 256, 0, stream>>>(ei0 + E0, ei1 + E1, ei2 + E2, cnt0, cnt1, cnt2);
  k_scan3<<<3, 64, 0, stream>>>(cnt0, off0, cur0, cnt1, off1, cur1, cnt2, off2, cur2);
  k_fill3<<<64, 256, 0, stream>>>(ei0 + E0, cur0, el0, ei1 + E1, cur1, el1, ei2 + E2, cur2, el2);
  k_bw3<<<64, 256, 0, stream>>>(d_in[2], d_in[4], d_in[6], Am, bw0, bw1, bw2, flagp);
  k_pcvt<<<4096, 256, 0, stream>>>(d_in[19], d_in[20], d_in[21], Pb1, Pb2, Pb3, flagp);

  // level 0 -> 1   (zx1:A fp32, h1:B bf16, hp1:A fp32)
  k_gather1<<<dim3(1, N0, B), 256, 0, stream>>>(xc, ei0, off0, el0, cnt0, bw0, (float*)Aa);
  k_cmix<4, 16, 0, float, bf16><<<dim3(4, N0, B), 256, 0, stream>>>((const float*)Aa, wc1, bias + 0, (bf16*)Bb, N0);
  k_pool_mfma<2, float><<<dim3(50, 4, B), 256, 0, stream>>>(Pb1, (const ushort_t*)Bb, (float*)Aa, 512, 2048, 3200);
  // level 1 -> 2   (zx2:B bf16, h2:A bf16, hp2:B fp32)
  k_gather<16, 4, bf16><<<dim3(4, N1, B), 256, 0, stream>>>((const float*)Aa, ei1, off1, el1, cnt1, bw1, (bf16*)Bb, N1);
  k_cmix<64, 32, 0, bf16, bf16><<<dim3(4, N1, B), 256, 0, stream>>>((const bf16*)Bb, wc2, bias + 16, (bf16*)Aa, N1);
  k_pool_mfma<1, float><<<dim3(100, 2, B), 256, 0, stream>>>(Pb2, (const ushort_t*)Aa, (float*)Bb, 128, 512, 6400);
  // level 2 -> 3   (zx3:A bf16, h3:B bf16, hp3:A fp32)
  k_gather<32, 8, bf16><<<dim3(4, N2, B), 256, 0, stream>>>((const float*)Bb, ei2, off2, el2, cnt2, bw2, (bf16*)Aa, N2);
  k_cmix<128, 64, 0, bf16, bf16><<<dim3(4, N2, B), 256, 0, stream>>>((const bf16*)Aa, wc3, bias + 48, (bf16*)Bb, N2);
  k_pool_mfma<1, float><<<dim3(200, 1, B), 256, 0, stream>>>(Pb3, (const ushort_t*)Bb, (float*)Aa, 64, 128, 12800);
  // head  (g:B fp32, mu:A fp32)
  k_cmix<64, 128, 0, float, float><<<dim3(4, N3, B), 256, 0, stream>>>((const float*)Aa, w1h, bias + 112, (float*)Bb, N3);
  k_cmix<128, 64, 1, float, float><<<dim3(4, N3, B), 256, 0, stream>>>((const float*)Bb, w2h, bias + 240, (float*)Aa, N3);
  k_store<<<6400, 256, 0, stream>>>((const float*)Aa, d_out, 1638400, flagp);
}

// Round 5
// 331.388 us; speedup vs baseline: 4.4265x; 1.2996x over previous
//
#include <hip/hip_runtime.h>
#include <hip/hip_bf16.h>

using bf16 = __hip_bfloat16;
typedef unsigned short ushort_t;
typedef unsigned int uint_t;

constexpr int B = 2, T = 200;
constexpr int N0 = 2048, N1 = 512, N2 = 128, N3 = 64;
constexpr int E0 = 16384, E1 = 8192, E2 = 2048;

typedef __attribute__((ext_vector_type(8))) short bf16x8;
typedef __attribute__((ext_vector_type(4))) float f32x4;

// runtime-dtype load: bf=1 -> bf16, bf=0 -> fp32
__device__ __forceinline__ float ldx(const void* p, long i, int bf) {
  if (bf) {
    uint_t v = (uint_t)(((const ushort_t*)p)[i]) << 16;
    float f; __builtin_memcpy(&f, &v, 4); return f;
  }
  return ((const float*)p)[i];
}
__device__ __forceinline__ float rdf(const float* p) { return *p; }
__device__ __forceinline__ float rdf(const bf16* p) { return __bfloat162float(*p); }
__device__ __forceinline__ void stf(float* p, float v) { *p = v; }
__device__ __forceinline__ void stf(bf16* p, float v) { *p = __float2bfloat16(v); }
__device__ __forceinline__ ushort_t f2bfu(float v) {
  bf16 h = __float2bfloat16(v); ushort_t u; __builtin_memcpy(&u, &h, 2); return u;
}
__device__ __forceinline__ ushort_t ldbf(const bf16* p) { ushort_t u; __builtin_memcpy(&u, p, 2); return u; }
__device__ __forceinline__ ushort_t ldbf(const float* p) { return f2bfu(*p); }

// ---------- setup kernels ----------
__global__ void k_zero_ints(int* p, int n) {
  int i = blockIdx.x * 256 + threadIdx.x;
  if (i < n) p[i] = 0;
}

// dtype probe: ea0 is uniform[0,1]. As true bf16 all 128 halves decode in [0,1].
__global__ void k_probe(const ushort_t* ea, int* flag) {
  if (threadIdx.x == 0 && blockIdx.x == 0) {
    int c = 0;
    for (int i = 0; i < 128; ++i) {
      uint_t v = (uint_t)ea[i] << 16;
      float f; __builtin_memcpy(&f, &v, 4);
      if (f >= 0.f && f <= 1.0f) c++;
    }
    *flag = (c >= 120) ? 1 : 0;
  }
}

// normalize all float-dtype params to fp32 in ws
__global__ void k_cvtall(const void* x, const void* Wk1, const void* Wr1,
                         const void* Wk2, const void* Wr2,
                         const void* Wk3, const void* Wr3,
                         const void* W1h, const void* W2h,
                         const void* b1, const void* b2, const void* b3,
                         const void* b1h, const void* b2h,
                         const void* A1, const void* A2, const void* A3,
                         float* dst, const int* flagp) {
  int i = blockIdx.x * 256 + threadIdx.x;
  int bf = *flagp;
  if (i < 819200)       dst[i] = ldx(x,   i, bf);
  else if (i < 819248)  dst[i] = ldx(Wk1, i - 819200, bf);
  else if (i < 819264)  dst[i] = ldx(Wr1, i - 819248, bf);
  else if (i < 820800)  dst[i] = ldx(Wk2, i - 819264, bf);
  else if (i < 821312)  dst[i] = ldx(Wr2, i - 820800, bf);
  else if (i < 827456)  dst[i] = ldx(Wk3, i - 821312, bf);
  else if (i < 829504)  dst[i] = ldx(Wr3, i - 827456, bf);
  else if (i < 837696)  dst[i] = ldx(W1h, i - 829504, bf);
  else if (i < 845888)  dst[i] = ldx(W2h, i - 837696, bf);
  else if (i < 845904)  dst[i] = ldx(b1,  i - 845888, bf);
  else if (i < 845936)  dst[i] = ldx(b2,  i - 845904, bf);
  else if (i < 846000)  dst[i] = ldx(b3,  i - 845936, bf);
  else if (i < 846128)  dst[i] = ldx(b1h, i - 846000, bf);
  else if (i < 846192)  dst[i] = ldx(b2h, i - 846128, bf);
  else if (i < 846201)  dst[i] = ldx(A1,  i - 846192, bf);
  else if (i < 846210)  dst[i] = ldx(A2,  i - 846201, bf);
  else if (i < 846219)  dst[i] = ldx(A3,  i - 846210, bf);
}

// transpose fp32 W [C][O] -> bf16 Wt [O][C] for MFMA A-operand staging
__global__ void k_wprep(const float* wc2, const float* wc3, const float* w1h, const float* w2h,
                        ushort_t* t2, ushort_t* t3, ushort_t* t1h, ushort_t* t2h) {
  int i = blockIdx.x * 256 + threadIdx.x;
  if (i < 2048) { int o = i >> 6, c = i & 63; t2[i] = f2bfu(wc2[c * 32 + o]); }
  else if (i < 10240) { int j = i - 2048; int o = j >> 7, c = j & 127; t3[j] = f2bfu(wc3[c * 64 + o]); }
  else if (i < 18432) { int j = i - 10240; int o = j >> 6, c = j & 63; t1h[j] = f2bfu(w1h[c * 128 + o]); }
  else if (i < 26624) { int j = i - 18432; int o = j >> 7, c = j & 127; t2h[j] = f2bfu(w2h[c * 64 + o]); }
}

__global__ void k_hist3(const int* d0, const int* d1, const int* d2,
                        int* c0, int* c1, int* c2) {
  int i = blockIdx.x * 256 + threadIdx.x;
  if (i < E0) atomicAdd(&c0[d0[i]], 1);
  if (i < E1) atomicAdd(&c1[d1[i]], 1);
  if (i < E2) atomicAdd(&c2[d2[i]], 1);
}

__global__ void k_scan3(const int* c0, int* o0, int* u0,
                        const int* c1, int* o1, int* u1,
                        const int* c2, int* o2, int* u2) {
  const int* cnt; int* off; int* cur; int N;
  if (blockIdx.x == 0)      { cnt = c0; off = o0; cur = u0; N = N0; }
  else if (blockIdx.x == 1) { cnt = c1; off = o1; cur = u1; N = N1; }
  else                      { cnt = c2; off = o2; cur = u2; N = N2; }
  int tid = threadIdx.x;
  int chunk = (N + 63) >> 6;
  int base = tid * chunk;
  int s = 0;
  for (int j = 0; j < chunk; ++j) { int idx = base + j; if (idx < N) s += cnt[idx]; }
  int pre = s;
  for (int d = 1; d < 64; d <<= 1) {
    int v = __shfl_up(pre, d, 64);
    if (tid >= d) pre += v;
  }
  int run = pre - s;
  for (int j = 0; j < chunk; ++j) {
    int idx = base + j;
    if (idx < N) { off[idx] = run; cur[idx] = run; run += cnt[idx]; }
  }
  if (tid == 63) off[N] = run;
}

__global__ void k_fill3(const int* d0, int* u0, int* e0l,
                        const int* d1, int* u1, int* e1l,
                        const int* d2, int* u2, int* e2l) {
  int i = blockIdx.x * 256 + threadIdx.x;
  if (i < E0) { int p = atomicAdd(&u0[d0[i]], 1); e0l[p] = i; }
  if (i < E1) { int p = atomicAdd(&u1[d1[i]], 1); e1l[p] = i; }
  if (i < E2) { int p = atomicAdd(&u2[d2[i]], 1); e2l[p] = i; }
}

__device__ __forceinline__ void bw_one(const void* ea, int bf, const float* A,
                                       float* bw, int e) {
  float a0 = ldx(ea, e*3+0, bf), a1 = ldx(ea, e*3+1, bf), a2 = ldx(ea, e*3+2, bf);
  float l0 = a0*A[0] + a1*A[3] + a2*A[6];
  float l1 = a0*A[1] + a1*A[4] + a2*A[7];
  float l2 = a0*A[2] + a1*A[5] + a2*A[8];
  float m = fmaxf(l0, fmaxf(l1, l2));
  float x0 = expf(l0 - m), x1 = expf(l1 - m), x2 = expf(l2 - m);
  float inv = 1.0f / (x0 + x1 + x2);
  bw[e*3+0] = x0*inv; bw[e*3+1] = x1*inv; bw[e*3+2] = x2*inv;
}

__global__ void k_bw3(const void* ea0, const void* ea1, const void* ea2,
                      const float* Am, float* bw0, float* bw1, float* bw2,
                      const int* flagp) {
  int bf = *flagp;
  int i = blockIdx.x * 256 + threadIdx.x;
  if (i < E0) bw_one(ea0, bf, Am + 0,  bw0, i);
  if (i < E1) bw_one(ea1, bf, Am + 9,  bw1, i);
  if (i < E2) bw_one(ea2, bf, Am + 18, bw2, i);
}

// P matrices -> bf16 [M][K]
__global__ void k_pcvt(const void* P01, const void* P12, const void* P23,
                       ushort_t* p1, ushort_t* p2, ushort_t* p3, const int* flagp) {
  int bf = *flagp;
  int i = blockIdx.x * 256 + threadIdx.x;
  if (i < 512 * 2048) p1[i] = f2bfu(ldx(P01, i, bf));
  if (i < 128 * 512)  p2[i] = f2bfu(ldx(P12, i, bf));
  if (i < 64 * 128)   p3[i] = f2bfu(ldx(P23, i, bf));
}

// ---------- fused level-1 gather + channel-mix (Cin=1 -> 16 ch), bf16 out ----------
__global__ __launch_bounds__(256) void k_gc1(const float* x, const int* src,
    const int* off, const int* elist, const int* cnt, const float* bw,
    const float* W, const float* bias, bf16* h1) {
  __shared__ float Wl[64];
  __shared__ float bl[16];
  int tid = threadIdx.x;
  if (tid < 64) Wl[tid] = W[tid];
  if (tid < 16) bl[tid] = bias[tid];
  __syncthreads();
  int n = blockIdx.y, b = blockIdx.z;
  int t = tid;
  if (t >= T) return;
  int beg = off[n], end = off[n + 1];
  float a0 = 0.f, a1 = 0.f, a2 = 0.f;
  for (int q = beg; q < end; ++q) {
    int e = elist[q];
    int s = src[e];
    float xv = x[(b * N0 + s) * T + t];
    a0 += bw[e*3+0] * xv; a1 += bw[e*3+1] * xv; a2 += bw[e*3+2] * xv;
  }
  int c = cnt[n];
  float inv = 1.f / (float)(c > 0 ? c : 1);
  a0 *= inv; a1 *= inv; a2 *= inv;
  float xr = x[(b * N0 + n) * T + t];
  bf16* op = h1 + ((long)(b * N0 + n) * 16) * T + t;
#pragma unroll
  for (int o = 0; o < 16; ++o) {
    float v = a0 * Wl[o] + a1 * Wl[16 + o] + a2 * Wl[32 + o] + xr * Wl[48 + o] + bl[o];
    v = v > 0.f ? v : (expf(v) - 1.f);
    op[o * T] = __float2bfloat16(v);
  }
}

// ---------- generic gather (fp32 in, bf16 out) ----------
template<int CIN, int CPI, typename TOut>
__global__ __launch_bounds__(256) void k_gather(const float* x, const int* src,
    const int* off, const int* elist, const int* cnt, const float* bw,
    TOut* zx, int N) {
  int tx = threadIdx.x & 63, iy = threadIdx.x >> 6;
  int t = blockIdx.x * 64 + tx;
  int n = blockIdx.y, b = blockIdx.z;
  if (t >= T) return;
  int beg = off[n], end = off[n + 1];
  float acc[3][CPI];
#pragma unroll
  for (int k = 0; k < 3; ++k)
#pragma unroll
    for (int j = 0; j < CPI; ++j) acc[k][j] = 0.f;
  for (int q = beg; q < end; ++q) {
    int e = elist[q];
    int s = src[e];
    float w0 = bw[e*3+0], w1 = bw[e*3+1], w2 = bw[e*3+2];
    const float* xp = x + ((long)(b * N + s) * CIN) * T + t;
#pragma unroll
    for (int j = 0; j < CPI; ++j) {
      int i = iy * CPI + j;
      float xv = xp[i * T];
      acc[0][j] += w0 * xv; acc[1][j] += w1 * xv; acc[2][j] += w2 * xv;
    }
  }
  int c = cnt[n];
  float inv = 1.f / (float)(c > 0 ? c : 1);
  TOut* zp = zx + ((long)(b * N + n) * 4 * CIN) * T + t;
  const float* xs = x + ((long)(b * N + n) * CIN) * T + t;
#pragma unroll
  for (int j = 0; j < CPI; ++j) {
    int i = iy * CPI + j;
    stf(zp + (0 * CIN + i) * T, acc[0][j] * inv);
    stf(zp + (1 * CIN + i) * T, acc[1][j] * inv);
    stf(zp + (2 * CIN + i) * T, acc[2][j] * inv);
    stf(zp + (3 * CIN + i) * T, xs[i * T]);
  }
}

// ---------- MFMA channel mix: out[b,n,o,t] = act(sum_c Wt[o,c]*in[b,n,c,t] + bias[o]) ----------
// Wt bf16 [O][C] in ws. Block = (64-t chunk, node, b); 4 waves; wave w owns t rows w*16..+15.
// ACT: 0=ELU, 1=tanh. OUTM: 0=bf16 out tensor; 1=runtime-flag dtype to d_out.
template<int C, int O, int ACT, typename TIn, int OUTM>
__global__ __launch_bounds__(256) void k_cmixm(const TIn* in, const ushort_t* Wt,
    const float* bias, void* outp, int N, const int* flagp) {
  constexpr int KG = C / 8;
  constexpr int MT = O / 16;
  __shared__ __align__(16) ushort_t Ws[O * C];
  __shared__ __align__(16) ushort_t Is[64 * C];
  int tid = threadIdx.x;
  int w = tid >> 6, l = tid & 63;
  int lf = l & 15, quad = l >> 4;
  int t0 = blockIdx.x * 64;
  int n = blockIdx.y, b = blockIdx.z;

  // stage W (bf16 [O][C], b128 coalesced, XOR-swizzled kg)
  {
    const uint4* Wg = (const uint4*)Wt;
    for (int s = tid; s < O * KG; s += 256) {
      int o = s / KG, kg = s % KG;
      uint4 v = Wg[s];
      *(uint4*)(Ws + o * C + ((kg ^ (o & 7)) * 8)) = v;
    }
  }
  // stage input tile transposed: Is[t][c] bf16 swizzled
  {
    const TIn* ip = in + ((long)(b * N + n) * C) * T + t0;
    int t = tid & 63;
    bool tok = (t0 + t) < T;
    for (int kg = tid >> 6; kg < KG; kg += 4) {
      ushort_t r[8];
#pragma unroll
      for (int j = 0; j < 8; ++j)
        r[j] = tok ? ldbf(ip + (kg * 8 + j) * T + t) : (ushort_t)0;
      *(uint4*)(Is + t * C + ((kg ^ (t & 7)) * 8)) = *(uint4*)r;
    }
  }
  __syncthreads();

  f32x4 acc[MT];
#pragma unroll
  for (int mt = 0; mt < MT; ++mt) acc[mt] = (f32x4){0.f, 0.f, 0.f, 0.f};
  int tr = w * 16 + lf;
#pragma unroll
  for (int kc = 0; kc < C / 32; ++kc) {
    int kg0 = kc * 4 + quad;
    bf16x8 bfr = *(const bf16x8*)(Is + tr * C + ((kg0 ^ (tr & 7)) * 8));
#pragma unroll
    for (int mt = 0; mt < MT; ++mt) {
      int o = mt * 16 + lf;
      bf16x8 afr = *(const bf16x8*)(Ws + o * C + ((kg0 ^ (o & 7)) * 8));
      acc[mt] = __builtin_amdgcn_mfma_f32_16x16x32_bf16(afr, bfr, acc[mt], 0, 0, 0);
    }
  }
  // epilogue: D[o = mt*16+quad*4+r][t = w*16+lf]
  int t = t0 + w * 16 + lf;
  if (t < T) {
    long nb = (long)(b * N + n) * O;
    int bfflag = OUTM ? *flagp : 1;
#pragma unroll
    for (int mt = 0; mt < MT; ++mt) {
#pragma unroll
      for (int r = 0; r < 4; ++r) {
        int o = mt * 16 + quad * 4 + r;
        float v = acc[mt][r] + bias[o];
        if (ACT == 0) v = v > 0.f ? v : (expf(v) - 1.f);
        else          v = tanhf(v);
        long idx = (nb + o) * T + t;
        if (OUTM == 0) ((bf16*)outp)[idx] = __float2bfloat16(v);
        else if (bfflag) ((bf16*)outp)[idx] = __float2bfloat16(v);
        else ((float*)outp)[idx] = v;
      }
    }
  }
}

// ---------- MFMA pool GEMM: out[b,m,f] = sum_k Pb[m,k] * h[b,k,f] ----------
template<int WMT, typename TOut>
__global__ __launch_bounds__(256) void k_pool_mfma(const ushort_t* Pb, const ushort_t* h,
                                                   TOut* out, int M, int K, int F) {
  constexpr int BM = 64 * WMT;
  __shared__ __align__(16) ushort_t As[BM * 64];
  __shared__ __align__(16) ushort_t Bs[64 * 64];
  int tid = threadIdx.x;
  int w = tid >> 6, l = tid & 63;
  int lf = l & 15, quad = l >> 4;
  int f0 = blockIdx.x * 64;
  int m0 = blockIdx.y * BM;
  int b = blockIdx.z;
  f32x4 acc[WMT][4];
#pragma unroll
  for (int wt = 0; wt < WMT; ++wt)
#pragma unroll
    for (int ft = 0; ft < 4; ++ft) acc[wt][ft] = (f32x4){0.f, 0.f, 0.f, 0.f};

  for (int k0 = 0; k0 < K; k0 += 64) {
#pragma unroll
    for (int it = 0; it < BM / 32; ++it) {
      int cc = tid + 256 * it;
      int m = cc >> 3, kc = cc & 7;
      uint4 v = *(const uint4*)(Pb + (long)(m0 + m) * K + k0 + kc * 8);
      *(uint4*)(As + m * 64 + ((kc ^ (m & 7)) * 8)) = v;
    }
    {
      int f = tid & 63, kb = (tid >> 6) * 16;
      const ushort_t* hp = h + ((long)(b * K + k0 + kb)) * F + f0 + f;
      ushort_t r[16];
#pragma unroll
      for (int i = 0; i < 16; ++i) r[i] = hp[(long)i * F];
      int kc0 = kb >> 3;
      *(uint4*)(Bs + f * 64 + ((kc0 ^ (f & 7)) * 8)) = *(uint4*)&r[0];
      *(uint4*)(Bs + f * 64 + (((kc0 + 1) ^ (f & 7)) * 8)) = *(uint4*)&r[8];
    }
    __syncthreads();
#pragma unroll
    for (int ks = 0; ks < 2; ++ks) {
      int kc = ks * 4 + quad;
      bf16x8 bfr[4];
#pragma unroll
      for (int ft = 0; ft < 4; ++ft) {
        int fl = ft * 16 + lf;
        bfr[ft] = *(const bf16x8*)(Bs + fl * 64 + ((kc ^ (fl & 7)) * 8));
      }
#pragma unroll
      for (int wt = 0; wt < WMT; ++wt) {
        int ml = wt * 64 + w * 16 + lf;
        bf16x8 afr = *(const bf16x8*)(As + ml * 64 + ((kc ^ (ml & 7)) * 8));
#pragma unroll
        for (int ft = 0; ft < 4; ++ft)
          acc[wt][ft] = __builtin_amdgcn_mfma_f32_16x16x32_bf16(afr, bfr[ft], acc[wt][ft], 0, 0, 0);
      }
    }
    __syncthreads();
  }
#pragma unroll
  for (int wt = 0; wt < WMT; ++wt) {
#pragma unroll
    for (int r = 0; r < 4; ++r) {
      int m = m0 + wt * 64 + w * 16 + quad * 4 + r;
      TOut* op = out + ((long)(b * M + m)) * F + f0 + lf;
#pragma unroll
      for (int ft = 0; ft < 4; ++ft)
        stf(op + ft * 16, acc[wt][ft][r]);
    }
  }
}

extern "C" void kernel_launch(void* const* d_in, const int* in_sizes, int n_in,
                              void* d_out, int out_size, void* d_ws, size_t ws_size,
                              hipStream_t stream) {
  const int* ei0 = (const int*)d_in[1];
  const int* ei1 = (const int*)d_in[3];
  const int* ei2 = (const int*)d_in[5];

  char* base = (char*)d_ws;
  int* I = (int*)base;
  int* cnt0 = I;         int* off0 = I + 2048;  int* cur0 = I + 4112;  int* el0 = I + 6160;
  int* cnt1 = I + 22544; int* off1 = I + 23056; int* cur1 = I + 23584; int* el1 = I + 24096;
  int* cnt2 = I + 32288; int* off2 = I + 32416; int* cur2 = I + 32560; int* el2 = I + 32688;
  int* flagp = I + 40448;
  float* Fb = (float*)(base + 163840);
  float* xc  = Fb + 0;
  float* wc1 = Fb + 819200;
  float* wc2 = Fb + 819264;
  float* wc3 = Fb + 821312;
  float* w1h = Fb + 829504;
  float* w2h = Fb + 837696;
  float* bias= Fb + 845888;   // b1@0 b2@16 b3@48 b1h@112 b2h@240
  float* Am  = Fb + 846192;   // A1@0 A2@9 A3@18
  float* bw0 = Fb + 846220;
  float* bw1 = Fb + 895372;
  float* bw2 = Fb + 919948;
  // repacked prep region (fits the old pt1-sized hole; all < float offset 2048512 = Aa start)
  ushort_t* Pb1 = (ushort_t*)(Fb + 926092);    // 1048576 ushorts -> ends float 1450380
  ushort_t* Pb2 = (ushort_t*)(Fb + 1450380);   // 65536 ushorts   -> ends 1483148
  ushort_t* Pb3 = (ushort_t*)(Fb + 1483148);   // 8192 ushorts    -> ends 1487244
  ushort_t* wt2  = (ushort_t*)(Fb + 1487244);  // 2048            -> ends 1488268
  ushort_t* wt3  = (ushort_t*)(Fb + 1488268);  // 8192            -> ends 1492364
  ushort_t* wt1h = (ushort_t*)(Fb + 1492364);  // 8192            -> ends 1496460
  ushort_t* wt2h = (ushort_t*)(Fb + 1496460);  // 8192            -> ends 1500556
  char* Aa = base + 8357888;    // arena A: 13,107,200 B
  char* Bb = base + 21465088;   // arena B: 26,214,400 B

  // setup
  k_zero_ints<<<160, 256, 0, stream>>>(I, 40960);
  k_probe<<<1, 64, 0, stream>>>((const ushort_t*)d_in[2], flagp);
  k_cvtall<<<3306, 256, 0, stream>>>(d_in[0], d_in[8], d_in[9], d_in[12], d_in[13],
                                     d_in[16], d_in[17], d_in[22], d_in[24],
                                     d_in[10], d_in[14], d_in[18], d_in[23], d_in[25],
                                     d_in[7], d_in[11], d_in[15], Fb, flagp);
  k_hist3<<<64, 256, 0, stream>>>(ei0 + E0, ei1 + E1, ei2 + E2, cnt0, cnt1, cnt2);
  k_scan3<<<3, 64, 0, stream>>>(cnt0, off0, cur0, cnt1, off1, cur1, cnt2, off2, cur2);
  k_fill3<<<64, 256, 0, stream>>>(ei0 + E0, cur0, el0, ei1 + E1, cur1, el1, ei2 + E2, cur2, el2);
  k_bw3<<<64, 256, 0, stream>>>(d_in[2], d_in[4], d_in[6], Am, bw0, bw1, bw2, flagp);
  k_pcvt<<<4096, 256, 0, stream>>>(d_in[19], d_in[20], d_in[21], Pb1, Pb2, Pb3, flagp);
  k_wprep<<<104, 256, 0, stream>>>(wc2, wc3, w1h, w2h, wt2, wt3, wt1h, wt2h);

  // level 0 -> 1: fused gather+cmix -> h1 bf16 (Bb), pool1 -> hp1 fp32 (Aa)
  k_gc1<<<dim3(1, N0, B), 256, 0, stream>>>(xc, ei0, off0, el0, cnt0, bw0, wc1, bias + 0, (bf16*)Bb);
  k_pool_mfma<2, float><<<dim3(50, 4, B), 256, 0, stream>>>(Pb1, (const ushort_t*)Bb, (float*)Aa, 512, 2048, 3200);
  // level 1 -> 2: gather -> zx2 bf16 (Bb), cmix MFMA -> h2 bf16 (Aa), pool2 -> hp2 fp32 (Bb)
  k_gather<16, 4, bf16><<<dim3(4, N1, B), 256, 0, stream>>>((const float*)Aa, ei1, off1, el1, cnt1, bw1, (bf16*)Bb, N1);
  k_cmixm<64, 32, 0, bf16, 0><<<dim3(4, N1, B), 256, 0, stream>>>((const bf16*)Bb, wt2, bias + 16, Aa, N1, flagp);
  k_pool_mfma<1, float><<<dim3(100, 2, B), 256, 0, stream>>>(Pb2, (const ushort_t*)Aa, (float*)Bb, 128, 512, 6400);
  // level 2 -> 3: gather -> zx3 bf16 (Aa), cmix MFMA -> h3 bf16 (Bb), pool3 -> hp3 fp32 (Aa)
  k_gather<32, 8, bf16><<<dim3(4, N2, B), 256, 0, stream>>>((const float*)Bb, ei2, off2, el2, cnt2, bw2, (bf16*)Aa, N2);
  k_cmixm<128, 64, 0, bf16, 0><<<dim3(4, N2, B), 256, 0, stream>>>((const bf16*)Aa, wt3, bias + 48, Bb, N2, flagp);
  k_pool_mfma<1, float><<<dim3(200, 1, B), 256, 0, stream>>>(Pb3, (const ushort_t*)Bb, (float*)Aa, 64, 128, 12800);
  // head: MFMA cmix -> g bf16 (Bb), MFMA cmix tanh -> d_out (runtime dtype)
  k_cmixm<64, 128, 0, float, 0><<<dim3(4, N3, B), 256, 0, stream>>>((const float*)Aa, wt1h, bias + 112, Bb, N3, flagp);
  k_cmixm<128, 64, 1, bf16, 1><<<dim3(4, N3, B), 256, 0, stream>>>((const bf16*)Bb, wt2h, bias + 240, d_out, N3, flagp);
}